// Round 5
// baseline (383.939 us; speedup 1.0000x reference)
//
#include <hip/hip_runtime.h>
#include <hip/hip_fp16.h>

// Problem dims
#define B_    512
#define S_    50
#define D_    100
#define NS_   12
#define LAST_ 3
#define NADJ_ 12
#define SCALE_ 0.1f

typedef __attribute__((ext_vector_type(4))) float f4;

__device__ __forceinline__ f4 ntload4(const float* p) {
    return __builtin_nontemporal_load((const f4*)p);
}

// load 4 consecutive fp16 from LDS -> float4 (8B aligned)
__device__ __forceinline__ float4 ldh4(const __half* p) {
    float2 fa = __half22float2(*(const __half2*)p);
    float2 fb = __half22float2(*(const __half2*)(p + 2));
    float4 r; r.x = fa.x; r.y = fa.y; r.z = fb.x; r.w = fb.y;
    return r;
}

// 5-row x 4-col FMA group for one 4-k slab, fp32 LDS buffer
#define GEMM_STEP(ACC, BUF, K, W0, W1, W2, W3)                                      \
    _Pragma("unroll")                                                                \
    for (int i = 0; i < 5; ++i) {                                                    \
        float4 x = *(const float4*)&BUF[sb + i][K];                                  \
        ACC[i][0] = fmaf(x.x,W0.x, fmaf(x.y,W1.x, fmaf(x.z,W2.x, fmaf(x.w,W3.x, ACC[i][0])))); \
        ACC[i][1] = fmaf(x.x,W0.y, fmaf(x.y,W1.y, fmaf(x.z,W2.y, fmaf(x.w,W3.y, ACC[i][1])))); \
        ACC[i][2] = fmaf(x.x,W0.z, fmaf(x.y,W1.z, fmaf(x.z,W2.z, fmaf(x.w,W3.z, ACC[i][2])))); \
        ACC[i][3] = fmaf(x.x,W0.w, fmaf(x.y,W1.w, fmaf(x.z,W2.w, fmaf(x.w,W3.w, ACC[i][3])))); \
    }
// same, fp16 LDS buffer
#define GEMM_STEP_H(ACC, BUF, K, W0, W1, W2, W3)                                    \
    _Pragma("unroll")                                                                \
    for (int i = 0; i < 5; ++i) {                                                    \
        float4 x = ldh4(&BUF[sb + i][K]);                                            \
        ACC[i][0] = fmaf(x.x,W0.x, fmaf(x.y,W1.x, fmaf(x.z,W2.x, fmaf(x.w,W3.x, ACC[i][0])))); \
        ACC[i][1] = fmaf(x.x,W0.y, fmaf(x.y,W1.y, fmaf(x.z,W2.y, fmaf(x.w,W3.y, ACC[i][1])))); \
        ACC[i][2] = fmaf(x.x,W0.z, fmaf(x.y,W1.z, fmaf(x.z,W2.z, fmaf(x.w,W3.z, ACC[i][2])))); \
        ACC[i][3] = fmaf(x.x,W0.w, fmaf(x.y,W1.w, fmaf(x.z,W2.w, fmaf(x.w,W3.w, ACC[i][3])))); \
    }

// agg-gather pipeline (I literal 0..4; q/agg in registers, alf fp16 in LDS)
#define AGG_ISSUE(I)                                                                 \
    {   int base = (sb + (I)) * NS_;                                                 \
        _Pragma("unroll")                                                            \
        for (int n = 0; n < NS_; ++n)                                                \
            q[n] = ntload4(emb + nid[base + n] * D_ + d4);                           \
    }
#define AGG_CONSUME(I)                                                               \
    {   int base = (sb + (I)) * NS_;                                                 \
        float av[NS_]; float mx = -1e30f;                                            \
        _Pragma("unroll")                                                            \
        for (int n = 0; n < NS_; ++n) { av[n] = __half2float(alfH[base + n]);        \
                                        mx = fmaxf(mx, av[n]); }                     \
        float sm = 0.f;                                                              \
        _Pragma("unroll")                                                            \
        for (int n = 0; n < NS_; ++n) { av[n] = __expf(av[n] - mx); sm += av[n]; }   \
        float inv = 1.f / sm;                                                        \
        _Pragma("unroll")                                                            \
        for (int n = 0; n < NS_; ++n) {                                              \
            float w = av[n] * inv;                                                   \
            agg[I][0] = fmaf(w, q[n].x, agg[I][0]);                                  \
            agg[I][1] = fmaf(w, q[n].y, agg[I][1]);                                  \
            agg[I][2] = fmaf(w, q[n].z, agg[I][2]);                                  \
            agg[I][3] = fmaf(w, q[n].w, agg[I][3]);                                  \
        }                                                                            \
    }

// ---------------------------------------------------------------------------
// Single merged kernel, 4 blocks/CU (LDS 40.6 KB, VGPR<=128): the whole
// 1024-block grid is co-resident (exactly 4/CU), 16 waves/CU.
//   blocks [0, B_)      : fused local(star) + global(neighbor) branch
//   blocks [B_, 2*B_)   : last-items attention branch (aliased buffers)
// h staged fp16 (accumulations stay fp32). adj fp16 union'd with ssq.
// Neighbor gather software-pipelined across phases; NT for one-use streams.
// ---------------------------------------------------------------------------
__global__ __launch_bounds__(256, 4) void fused_all(
    const int* __restrict__ inputs,       // [B,S]
    const float* __restrict__ adj,        // [B,S,S]
    const float* __restrict__ emb,        // [N,D]
    const int* __restrict__ adj_all,      // [N,NS]
    const float* __restrict__ num_w,      // [N,NS]
    const float* __restrict__ sW,         // [2]
    const float* __restrict__ Wa,         // [D,D]
    const float* __restrict__ Wq,         // [D,D]
    const float* __restrict__ Wk,         // [D,D]
    const float* __restrict__ Wg,         // [2D,D]
    const int* __restrict__ last_items,   // [B,LAST]
    const int* __restrict__ adj_items,    // [B,LAST*NADJ]
    const float* __restrict__ Wl,         // [D,D]
    float* __restrict__ out)              // [B,S,D] then [B,D]
{
    __shared__ __align__(16) union HU {               // 10000 B
        __half h[S_][D_];                             //  h tile fp16
        float  ihf[LAST_][D_];                        //  last: item_h fp32
    } hu;
    __shared__ __align__(16) union WU {               // 20000 B
        float w[S_][D_];                              //  adjh, later agg (fp32)
        float ah[LAST_][NADJ_][D_];                   //  last: adj_h fp32
    } wu;
    __shared__ __align__(16) union US {               //  5000 B
        __half adjH[S_][S_];                          //  adj tile fp16 (dead after P2)
        float  ssq[S_][25];                           //  row-sumsq partials
        float  att[LAST_][NADJ_];                     //  last: attention
    } u;
    __shared__ __align__(16) float sk[300];           //  1200 B star|kb|kq ; last: qL
    __shared__ float gate[S_], rinv[S_], rinv2[S_];   //   600 B
    __shared__ int   ids[S_];                         //   200 B
    __shared__ int   nid[S_ * NS_];                   //  2400 B
    __shared__ __half alfH[S_ * NS_];                 //  1200 B (raw num_w, fp16)
    __shared__ float denom;
    // total ~40.6 KB -> 4 blocks/CU

    const int t = threadIdx.x;

    // =====================================================================
    // last-items branch
    // =====================================================================
    if (blockIdx.x >= B_) {
        const int b = blockIdx.x - B_;
        if (t < LAST_) ids[t] = last_items[b * LAST_ + t];
        if (t < LAST_ * NADJ_) nid[t] = adj_items[b * LAST_ * NADJ_ + t];
        __syncthreads();

        for (int e = t; e < LAST_ * 25; e += 256) {           // 75 quads
            int l = e / 25, dq = e - l * 25;
            *((f4*)&hu.ihf[0][0] + e) = ntload4(emb + ids[l] * D_ + dq * 4);
        }
        for (int e = t; e < LAST_ * NADJ_ * 25; e += 256) {   // 900 quads
            int j = e / 25, dq = e - j * 25;
            *((f4*)&wu.ah[0][0][0] + e) = ntload4(emb + nid[j] * D_ + dq * 4);
        }
        __syncthreads();

        // q = item_h @ Wl (coalesced column reads over d) -> sk
        for (int e = t; e < LAST_ * D_; e += 256) {
            int l = e / D_, d = e - l * D_;
            float a = 0.f;
            for (int k = 0; k < D_; ++k) a = fmaf(hu.ihf[l][k], Wl[k * D_ + d], a);
            sk[e] = a;
        }
        __syncthreads();

        if (t < LAST_ * NADJ_) {
            int l = t / NADJ_, n = t - l * NADJ_;
            const float* ar = &wu.ah[l][n][0];
            const float* qr = &sk[l * D_];
            float a = 0.f;
            for (int d = 0; d < D_; ++d) a = fmaf(qr[d], ar[d], a);
            u.att[l][n] = a * SCALE_;
        }
        __syncthreads();

        if (t < LAST_) {
            float mx = -1e30f;
            for (int n = 0; n < NADJ_; ++n) mx = fmaxf(mx, u.att[t][n]);
            float ex[NADJ_]; float sm = 0.f;
            for (int n = 0; n < NADJ_; ++n) { ex[n] = __expf(u.att[t][n] - mx); sm += ex[n]; }
            float inv = 1.f / sm;
            for (int n = 0; n < NADJ_; ++n) u.att[t][n] = ex[n] * inv;
        }
        __syncthreads();

        if (t < D_) {
            float acc = 0.f;
            for (int l = 0; l < LAST_; ++l) {
                float a = hu.ihf[l][t];
                for (int n = 0; n < NADJ_; ++n)
                    a = fmaf(u.att[l][n], wu.ah[l][n][t], a);
                acc += a;
            }
            __builtin_nontemporal_store(acc * (1.f / 3.f),
                                        out + B_ * S_ * D_ + b * D_ + t);
        }
        return;
    }

    // =====================================================================
    // fused star + neighbor branch
    // =====================================================================
    const int b = blockIdx.x;
    const float s0 = sW[0], s1 = sW[1];
    float* star = sk;           // [100]
    float* kb   = sk + 100;     // [100]
    float* kq   = sk + 200;     // [100]

    const bool act = (t < 250);
    int sg = 0, dg = 0, sb = 0, d4 = 0;
    if (act) { sg = t / 25; dg = t - sg * 25; sb = sg * 5; d4 = dg * 4; }

    // P0: ids
    if (t < S_) ids[t] = inputs[b * S_ + t];
    __syncthreads();

    // P1: denom ballot + gathers (h->fp16, adj->fp16, neighbor meta)
    if (t < 64) {
        unsigned long long m = __ballot(t < S_ && ids[t] != 0);
        if (t == 0) denom = fmaxf((float)__popcll(m), 1.f);
    }
    for (int e = t; e < S_ * 25; e += 256) {                  // 1250 quads
        int s = e / 25, dq = e - s * 25;
        f4 v = ntload4(emb + ids[s] * D_ + dq * 4);
        __half2* dst = (__half2*)&hu.h[s][dq * 4];
        dst[0] = __floats2half2_rn(v.x, v.y);
        dst[1] = __floats2half2_rn(v.z, v.w);
    }
    {
        __half2* dst = (__half2*)&u.adjH[0][0];
        const float* src = adj + b * S_ * S_;
        for (int e = t; e < S_ * S_ / 4; e += 256) {          // 625 quads
            f4 v = ntload4(src + e * 4);
            dst[2 * e]     = __floats2half2_rn(v.x, v.y);
            dst[2 * e + 1] = __floats2half2_rn(v.z, v.w);
        }
    }
    for (int e = t; e < S_ * NS_; e += 256) {                 // 600
        int r = e / NS_, n = e - r * NS_;
        nid[e]  = adj_all[ids[r] * NS_ + n];
        alfH[e] = __float2half(num_w[ids[r] * NS_ + n]);
    }
    __syncthreads();

    // pipelined neighbor gather state (registers)
    f4 q[NS_];
    float agg[5][4] = {};

    // ---- P2: issue gather 0; adjh = adj @ h -> wu.w (fp32); star ----
    if (act) {
        AGG_ISSUE(0)
        float acc[5][4] = {};
        for (int k = 0; k < S_; k += 2) {
            float4 w0 = ldh4(&hu.h[k][d4]);
            float4 w1 = ldh4(&hu.h[k + 1][d4]);
#pragma unroll
            for (int i = 0; i < 5; ++i) {
                float2 a2 = __half22float2(*(const __half2*)&u.adjH[sb + i][k]);
                acc[i][0] = fmaf(a2.x, w0.x, fmaf(a2.y, w1.x, acc[i][0]));
                acc[i][1] = fmaf(a2.x, w0.y, fmaf(a2.y, w1.y, acc[i][1]));
                acc[i][2] = fmaf(a2.x, w0.z, fmaf(a2.y, w1.z, acc[i][2]));
                acc[i][3] = fmaf(a2.x, w0.w, fmaf(a2.y, w1.w, acc[i][3]));
            }
        }
#pragma unroll
        for (int i = 0; i < 5; ++i) {
            float4 v; v.x = acc[i][0]; v.y = acc[i][1]; v.z = acc[i][2]; v.w = acc[i][3];
            *(float4*)&wu.w[sb + i][d4] = v;
        }
    }
    if (t < D_) {
        float a = 0.f;
        for (int s = 0; s < S_; ++s) a += (ids[s] != 0) ? __half2float(hu.h[s][t]) : 0.f;
        star[t] = a / denom;
    }
    __syncthreads();

    // ---- P3: consume0/issue1; kb = star@Wk; hn = adjh @ Wa (regs) ----
    float hn[5][4] = {};
    if (act) { AGG_CONSUME(0) AGG_ISSUE(1) }
    if (t < D_) {
        float a = 0.f;
        for (int k = 0; k < D_; ++k) a = fmaf(star[k], Wk[k * D_ + t], a);
        kb[t] = a;
    }
    if (act) {
        const float4* WaQ = (const float4*)Wa;
        for (int k = 0; k < D_; k += 4) {
            float4 w0 = WaQ[(k + 0) * 25 + dg], w1 = WaQ[(k + 1) * 25 + dg],
                   w2 = WaQ[(k + 2) * 25 + dg], w3 = WaQ[(k + 3) * 25 + dg];
            GEMM_STEP(hn, wu.w, k, w0, w1, w2, w3)
        }
    }
    __syncthreads();

    // ---- P3b: kq[t] = Wq[t,:]·kb ; consume1/issue2 ----
    if (t < D_) {
        float a = 0.f;
        const float4* wr = (const float4*)(Wq + t * D_);
#pragma unroll 5
        for (int j = 0; j < 25; ++j) {
            float4 uq = wr[j]; int k = j * 4;
            a = fmaf(uq.x, kb[k + 0], a); a = fmaf(uq.y, kb[k + 1], a);
            a = fmaf(uq.z, kb[k + 2], a); a = fmaf(uq.w, kb[k + 3], a);
        }
        kq[t] = a;
    }
    if (act) { AGG_CONSUME(1) AGG_ISSUE(2) }
    __syncthreads();

    // ---- P4: gate; consume2/issue3 ----
    if (t < S_) {
        float a = 0.f;
#pragma unroll 10
        for (int j = 0; j < 50; ++j) {
            float2 hv = __half22float2(*(const __half2*)&hu.h[t][2 * j]);
            a = fmaf(hv.x, kq[2 * j], fmaf(hv.y, kq[2 * j + 1], a));
        }
        gate[t] = 1.f / (1.f + __expf(-a * SCALE_));
    }
    if (act) { AGG_CONSUME(2) AGG_ISSUE(3) }
    __syncthreads();

    // ---- P5: hl = (1-g)*hn + g*star; ssq; consume3/issue4 ----
    float hl[5][4];
    if (act) {
#pragma unroll
        for (int i = 0; i < 5; ++i) {
            float g = gate[sb + i];
#pragma unroll
            for (int j = 0; j < 4; ++j)
                hl[i][j] = (1.f - g) * hn[i][j] + g * star[d4 + j];
            u.ssq[sb + i][dg] = hl[i][0]*hl[i][0] + hl[i][1]*hl[i][1]
                              + hl[i][2]*hl[i][2] + hl[i][3]*hl[i][3];
        }
        AGG_CONSUME(3) AGG_ISSUE(4)
    }
    __syncthreads();

    // ---- P6: rinv; consume4 ----
    if (t < S_) {
        float ss = 0.f;
#pragma unroll
        for (int j = 0; j < 25; ++j) ss += u.ssq[t][j];
        rinv[t] = s0 / fmaxf(sqrtf(ss), 1e-12f);
    }
    if (act) { AGG_CONSUME(4) }
    __syncthreads();

    // ---- P7: agg -> wu.w; normalize hl ----
    if (act) {
#pragma unroll
        for (int i = 0; i < 5; ++i) {
            float4 v; v.x = agg[i][0]; v.y = agg[i][1]; v.z = agg[i][2]; v.w = agg[i][3];
            *(float4*)&wu.w[sb + i][d4] = v;    // adjh reads finished in P3
        }
#pragma unroll
        for (int i = 0; i < 5; ++i) {
            float f = rinv[sb + i];
#pragma unroll
            for (int j = 0; j < 4; ++j) hl[i][j] *= f;
        }
    }
    __syncthreads();

    // ---- P8: hg = relu([h | agg] @ Wg); ssq ----
    float o[5][4] = {};
    if (act) {
        const float4* WgQ = (const float4*)Wg;
        for (int k = 0; k < D_; k += 4) {
            float4 w0 = WgQ[(k + 0) * 25 + dg], w1 = WgQ[(k + 1) * 25 + dg],
                   w2 = WgQ[(k + 2) * 25 + dg], w3 = WgQ[(k + 3) * 25 + dg];
            GEMM_STEP_H(o, hu.h, k, w0, w1, w2, w3)
        }
        for (int k = 0; k < D_; k += 4) {
            float4 w0 = WgQ[(D_ + k + 0) * 25 + dg], w1 = WgQ[(D_ + k + 1) * 25 + dg],
                   w2 = WgQ[(D_ + k + 2) * 25 + dg], w3 = WgQ[(D_ + k + 3) * 25 + dg];
            GEMM_STEP(o, wu.w, k, w0, w1, w2, w3)
        }
#pragma unroll
        for (int i = 0; i < 5; ++i) {
#pragma unroll
            for (int j = 0; j < 4; ++j) o[i][j] = fmaxf(o[i][j], 0.f);
            u.ssq[sb + i][dg] = o[i][0]*o[i][0] + o[i][1]*o[i][1]
                              + o[i][2]*o[i][2] + o[i][3]*o[i][3];
        }
    }
    __syncthreads();

    // ---- P9: rinv2 ----
    if (t < S_) {
        float ss = 0.f;
#pragma unroll
        for (int j = 0; j < 25; ++j) ss += u.ssq[t][j];
        rinv2[t] = s1 / fmaxf(sqrtf(ss), 1e-12f);
    }
    __syncthreads();

    // ---- P10: combine + NT store ----
    if (act) {
#pragma unroll
        for (int i = 0; i < 5; ++i) {
            float f = rinv2[sb + i];
            int row = b * S_ + sb + i;
            f4 ov;
            ov.x = hl[i][0] + o[i][0] * f;
            ov.y = hl[i][1] + o[i][1] * f;
            ov.z = hl[i][2] + o[i][2] * f;
            ov.w = hl[i][3] + o[i][3] * f;
            __builtin_nontemporal_store(ov, (f4*)(out + row * D_) + dg);
        }
    }
}

// ---------------------------------------------------------------------------
extern "C" void kernel_launch(void* const* d_in, const int* in_sizes, int n_in,
                              void* d_out, int out_size, void* d_ws, size_t ws_size,
                              hipStream_t stream) {
    (void)in_sizes; (void)n_in; (void)out_size; (void)d_ws; (void)ws_size;
    const int* inputs     = (const int*)d_in[0];
    const float* adj      = (const float*)d_in[1];
    // d_in[2] = item (unused by reference)
    const int* last_items = (const int*)d_in[3];
    const int* adj_items  = (const int*)d_in[4];
    const float* emb      = (const float*)d_in[5];
    const float* sW       = (const float*)d_in[6];
    const float* Wa       = (const float*)d_in[7];
    const float* Wq       = (const float*)d_in[8];
    const float* Wk       = (const float*)d_in[9];
    const float* Wg       = (const float*)d_in[10];
    const float* Wl       = (const float*)d_in[11];
    const int* adj_all    = (const int*)d_in[12];
    const float* num_w    = (const float*)d_in[13];

    float* out = (float*)d_out;

    fused_all<<<2 * B_, 256, 0, stream>>>(inputs, adj, emb, adj_all, num_w,
                                          sW, Wa, Wq, Wk, Wg,
                                          last_items, adj_items, Wl, out);
}

// Round 6
// 346.910 us; speedup vs baseline: 1.1067x; 1.1067x over previous
//
#include <hip/hip_runtime.h>
#include <hip/hip_fp16.h>

// Problem dims
#define B_    512
#define S_    50
#define D_    100
#define NS_   12
#define LAST_ 3
#define NADJ_ 12
#define SCALE_ 0.1f

typedef __attribute__((ext_vector_type(4))) float f4;

__device__ __forceinline__ f4 ntload4(const float* p) {
    return __builtin_nontemporal_load((const f4*)p);
}

// load 4 consecutive fp16 from LDS -> float4 (8B aligned)
__device__ __forceinline__ float4 ldh4(const __half* p) {
    float2 fa = __half22float2(*(const __half2*)p);
    float2 fb = __half22float2(*(const __half2*)(p + 2));
    float4 r; r.x = fa.x; r.y = fa.y; r.z = fb.x; r.w = fb.y;
    return r;
}

// 5-row x 4-col FMA group for one 4-k slab, fp32 LDS buffer
#define GEMM_STEP(ACC, BUF, K, W0, W1, W2, W3)                                      \
    _Pragma("unroll")                                                                \
    for (int i = 0; i < 5; ++i) {                                                    \
        float4 x = *(const float4*)&BUF[sb + i][K];                                  \
        ACC[i][0] = fmaf(x.x,W0.x, fmaf(x.y,W1.x, fmaf(x.z,W2.x, fmaf(x.w,W3.x, ACC[i][0])))); \
        ACC[i][1] = fmaf(x.x,W0.y, fmaf(x.y,W1.y, fmaf(x.z,W2.y, fmaf(x.w,W3.y, ACC[i][1])))); \
        ACC[i][2] = fmaf(x.x,W0.z, fmaf(x.y,W1.z, fmaf(x.z,W2.z, fmaf(x.w,W3.z, ACC[i][2])))); \
        ACC[i][3] = fmaf(x.x,W0.w, fmaf(x.y,W1.w, fmaf(x.z,W2.w, fmaf(x.w,W3.w, ACC[i][3])))); \
    }
// same, fp16 LDS buffer
#define GEMM_STEP_H(ACC, BUF, K, W0, W1, W2, W3)                                    \
    _Pragma("unroll")                                                                \
    for (int i = 0; i < 5; ++i) {                                                    \
        float4 x = ldh4(&BUF[sb + i][K]);                                            \
        ACC[i][0] = fmaf(x.x,W0.x, fmaf(x.y,W1.x, fmaf(x.z,W2.x, fmaf(x.w,W3.x, ACC[i][0])))); \
        ACC[i][1] = fmaf(x.x,W0.y, fmaf(x.y,W1.y, fmaf(x.z,W2.y, fmaf(x.w,W3.y, ACC[i][1])))); \
        ACC[i][2] = fmaf(x.x,W0.z, fmaf(x.y,W1.z, fmaf(x.z,W2.z, fmaf(x.w,W3.z, ACC[i][2])))); \
        ACC[i][3] = fmaf(x.x,W0.w, fmaf(x.y,W1.w, fmaf(x.z,W2.w, fmaf(x.w,W3.w, ACC[i][3])))); \
    }

// neighbor-gather pipeline: issue one row's 12 rows-of-emb quads into q[],
// consume computes the softmax-weighted sum and writes the FINISHED row
// directly to wu.w (free after the P3 barrier) — no agg registers.
#define AGG_ISSUE(I)                                                                 \
    {   int base = (sb + (I)) * NS_;                                                 \
        _Pragma("unroll")                                                            \
        for (int n = 0; n < NS_; ++n)                                                \
            q[n] = ntload4(emb + nid[base + n] * D_ + d4);                           \
    }
#define AGG_CONSUME(I)                                                               \
    {   int base = (sb + (I)) * NS_;                                                 \
        float av[NS_]; float mx = -1e30f;                                            \
        _Pragma("unroll")                                                            \
        for (int n = 0; n < NS_; ++n) { av[n] = __half2float(alfH[base + n]);        \
                                        mx = fmaxf(mx, av[n]); }                     \
        float sm = 0.f;                                                              \
        _Pragma("unroll")                                                            \
        for (int n = 0; n < NS_; ++n) { av[n] = __expf(av[n] - mx); sm += av[n]; }   \
        float inv = 1.f / sm;                                                        \
        float4 a; a.x = 0.f; a.y = 0.f; a.z = 0.f; a.w = 0.f;                        \
        _Pragma("unroll")                                                            \
        for (int n = 0; n < NS_; ++n) {                                              \
            float w = av[n] * inv;                                                   \
            a.x = fmaf(w, q[n].x, a.x); a.y = fmaf(w, q[n].y, a.y);                  \
            a.z = fmaf(w, q[n].z, a.z); a.w = fmaf(w, q[n].w, a.w);                  \
        }                                                                            \
        *(float4*)&wu.w[sb + (I)][d4] = a;                                           \
    }

// ---------------------------------------------------------------------------
// Single merged kernel, 4 blocks/CU (LDS 40.6 KB). waves_per_eu pinned (4,4)
// so the RA budget is 128 VGPR (R5 evidence: open-ended range made the RA
// target 8 waves -> 64 VGPR -> ~70 MB scratch spill traffic).
//   blocks [0, B_)      : fused local(star) + global(neighbor) branch
//   blocks [B_, 2*B_)   : last-items attention branch (aliased buffers)
// ---------------------------------------------------------------------------
__global__ __launch_bounds__(256)
__attribute__((amdgpu_waves_per_eu(4, 4)))
void fused_all(
    const int* __restrict__ inputs,       // [B,S]
    const float* __restrict__ adj,        // [B,S,S]
    const float* __restrict__ emb,        // [N,D]
    const int* __restrict__ adj_all,      // [N,NS]
    const float* __restrict__ num_w,      // [N,NS]
    const float* __restrict__ sW,         // [2]
    const float* __restrict__ Wa,         // [D,D]
    const float* __restrict__ Wq,         // [D,D]
    const float* __restrict__ Wk,         // [D,D]
    const float* __restrict__ Wg,         // [2D,D]
    const int* __restrict__ last_items,   // [B,LAST]
    const int* __restrict__ adj_items,    // [B,LAST*NADJ]
    const float* __restrict__ Wl,         // [D,D]
    float* __restrict__ out)              // [B,S,D] then [B,D]
{
    __shared__ __align__(16) union HU {               // 10000 B
        __half h[S_][D_];                             //  h tile fp16
        float  ihf[LAST_][D_];                        //  last: item_h fp32
    } hu;
    __shared__ __align__(16) union WU {               // 20000 B
        float w[S_][D_];                              //  adjh, later agg (fp32)
        float ah[LAST_][NADJ_][D_];                   //  last: adj_h fp32
    } wu;
    __shared__ __align__(16) union US {               //  5000 B
        __half adjH[S_][S_];                          //  adj tile fp16 (dead after P2)
        float  ssq[S_][25];                           //  row-sumsq partials
        float  att[LAST_][NADJ_];                     //  last: attention
    } u;
    __shared__ __align__(16) float sk[300];           //  1200 B star|kb|kq ; last: qL
    __shared__ float gate[S_], rinv[S_], rinv2[S_];   //   600 B
    __shared__ int   ids[S_];                         //   200 B
    __shared__ int   nid[S_ * NS_];                   //  2400 B
    __shared__ __half alfH[S_ * NS_];                 //  1200 B (raw num_w, fp16)
    __shared__ float denom;
    // total ~40.6 KB -> 4 blocks/CU

    const int t = threadIdx.x;

    // =====================================================================
    // last-items branch
    // =====================================================================
    if (blockIdx.x >= B_) {
        const int b = blockIdx.x - B_;
        if (t < LAST_) ids[t] = last_items[b * LAST_ + t];
        if (t < LAST_ * NADJ_) nid[t] = adj_items[b * LAST_ * NADJ_ + t];
        __syncthreads();

        for (int e = t; e < LAST_ * 25; e += 256) {           // 75 quads
            int l = e / 25, dq = e - l * 25;
            *((f4*)&hu.ihf[0][0] + e) = ntload4(emb + ids[l] * D_ + dq * 4);
        }
        for (int e = t; e < LAST_ * NADJ_ * 25; e += 256) {   // 900 quads
            int j = e / 25, dq = e - j * 25;
            *((f4*)&wu.ah[0][0][0] + e) = ntload4(emb + nid[j] * D_ + dq * 4);
        }
        __syncthreads();

        // q = item_h @ Wl (coalesced column reads over d) -> sk
        for (int e = t; e < LAST_ * D_; e += 256) {
            int l = e / D_, d = e - l * D_;
            float a = 0.f;
            for (int k = 0; k < D_; ++k) a = fmaf(hu.ihf[l][k], Wl[k * D_ + d], a);
            sk[e] = a;
        }
        __syncthreads();

        if (t < LAST_ * NADJ_) {
            int l = t / NADJ_, n = t - l * NADJ_;
            const float* ar = &wu.ah[l][n][0];
            const float* qr = &sk[l * D_];
            float a = 0.f;
            for (int d = 0; d < D_; ++d) a = fmaf(qr[d], ar[d], a);
            u.att[l][n] = a * SCALE_;
        }
        __syncthreads();

        if (t < LAST_) {
            float mx = -1e30f;
            for (int n = 0; n < NADJ_; ++n) mx = fmaxf(mx, u.att[t][n]);
            float ex[NADJ_]; float sm = 0.f;
            for (int n = 0; n < NADJ_; ++n) { ex[n] = __expf(u.att[t][n] - mx); sm += ex[n]; }
            float inv = 1.f / sm;
            for (int n = 0; n < NADJ_; ++n) u.att[t][n] = ex[n] * inv;
        }
        __syncthreads();

        if (t < D_) {
            float acc = 0.f;
            for (int l = 0; l < LAST_; ++l) {
                float a = hu.ihf[l][t];
                for (int n = 0; n < NADJ_; ++n)
                    a = fmaf(u.att[l][n], wu.ah[l][n][t], a);
                acc += a;
            }
            __builtin_nontemporal_store(acc * (1.f / 3.f),
                                        out + B_ * S_ * D_ + b * D_ + t);
        }
        return;
    }

    // =====================================================================
    // fused star + neighbor branch
    // =====================================================================
    const int b = blockIdx.x;
    const float s0 = sW[0], s1 = sW[1];
    float* star = sk;           // [100]
    float* kb   = sk + 100;     // [100]
    float* kq   = sk + 200;     // [100]

    const bool act = (t < 250);
    int sg = 0, dg = 0, sb = 0, d4 = 0;
    if (act) { sg = t / 25; dg = t - sg * 25; sb = sg * 5; d4 = dg * 4; }

    // P0: ids
    if (t < S_) ids[t] = inputs[b * S_ + t];
    __syncthreads();

    // P1: denom ballot + gathers (h->fp16, adj->fp16, neighbor meta)
    if (t < 64) {
        unsigned long long m = __ballot(t < S_ && ids[t] != 0);
        if (t == 0) denom = fmaxf((float)__popcll(m), 1.f);
    }
    for (int e = t; e < S_ * 25; e += 256) {                  // 1250 quads
        int s = e / 25, dq = e - s * 25;
        f4 v = ntload4(emb + ids[s] * D_ + dq * 4);
        __half2* dst = (__half2*)&hu.h[s][dq * 4];
        dst[0] = __floats2half2_rn(v.x, v.y);
        dst[1] = __floats2half2_rn(v.z, v.w);
    }
    {
        __half2* dst = (__half2*)&u.adjH[0][0];
        const float* src = adj + b * S_ * S_;
        for (int e = t; e < S_ * S_ / 4; e += 256) {          // 625 quads
            f4 v = ntload4(src + e * 4);
            dst[2 * e]     = __floats2half2_rn(v.x, v.y);
            dst[2 * e + 1] = __floats2half2_rn(v.z, v.w);
        }
    }
    for (int e = t; e < S_ * NS_; e += 256) {                 // 600
        int r = e / NS_, n = e - r * NS_;
        nid[e]  = adj_all[ids[r] * NS_ + n];
        alfH[e] = __float2half(num_w[ids[r] * NS_ + n]);
    }
    __syncthreads();

    f4 q[NS_];   // in-flight neighbor row (pipelined)

    // ---- P2: issue gather 0; adjh = adj @ h -> wu.w (fp32); star ----
    if (act) {
        AGG_ISSUE(0)
        float acc[5][4] = {};
        for (int k = 0; k < S_; k += 2) {
            float4 w0 = ldh4(&hu.h[k][d4]);
            float4 w1 = ldh4(&hu.h[k + 1][d4]);
#pragma unroll
            for (int i = 0; i < 5; ++i) {
                float2 a2 = __half22float2(*(const __half2*)&u.adjH[sb + i][k]);
                acc[i][0] = fmaf(a2.x, w0.x, fmaf(a2.y, w1.x, acc[i][0]));
                acc[i][1] = fmaf(a2.x, w0.y, fmaf(a2.y, w1.y, acc[i][1]));
                acc[i][2] = fmaf(a2.x, w0.z, fmaf(a2.y, w1.z, acc[i][2]));
                acc[i][3] = fmaf(a2.x, w0.w, fmaf(a2.y, w1.w, acc[i][3]));
            }
        }
#pragma unroll
        for (int i = 0; i < 5; ++i) {
            float4 v; v.x = acc[i][0]; v.y = acc[i][1]; v.z = acc[i][2]; v.w = acc[i][3];
            *(float4*)&wu.w[sb + i][d4] = v;
        }
    }
    if (t < D_) {
        float a = 0.f;
        for (int s = 0; s < S_; ++s) a += (ids[s] != 0) ? __half2float(hu.h[s][t]) : 0.f;
        star[t] = a / denom;
    }
    __syncthreads();

    // ---- P3: kb = star@Wk; hl(acc) = adjh @ Wa  (reads all of wu.w) ----
    float hl[5][4] = {};
    if (t < D_) {
        float a = 0.f;
        for (int k = 0; k < D_; ++k) a = fmaf(star[k], Wk[k * D_ + t], a);
        kb[t] = a;
    }
    if (act) {
        const float4* WaQ = (const float4*)Wa;
        for (int k = 0; k < D_; k += 4) {
            float4 w0 = WaQ[(k + 0) * 25 + dg], w1 = WaQ[(k + 1) * 25 + dg],
                   w2 = WaQ[(k + 2) * 25 + dg], w3 = WaQ[(k + 3) * 25 + dg];
            GEMM_STEP(hl, wu.w, k, w0, w1, w2, w3)
        }
    }
    __syncthreads();   // wu.w (adjh) fully consumed -> rows reusable for agg

    // ---- P3b: kq = Wq·kb; consume0 -> wu.w; issue1 ----
    if (t < D_) {
        float a = 0.f;
        const float4* wr = (const float4*)(Wq + t * D_);
#pragma unroll 5
        for (int j = 0; j < 25; ++j) {
            float4 uq = wr[j]; int k = j * 4;
            a = fmaf(uq.x, kb[k + 0], a); a = fmaf(uq.y, kb[k + 1], a);
            a = fmaf(uq.z, kb[k + 2], a); a = fmaf(uq.w, kb[k + 3], a);
        }
        kq[t] = a;
    }
    if (act) { AGG_CONSUME(0) AGG_ISSUE(1) }
    __syncthreads();

    // ---- P4: gate; consume1; issue2 ----
    if (t < S_) {
        float a = 0.f;
#pragma unroll 10
        for (int j = 0; j < 50; ++j) {
            float2 hv = __half22float2(*(const __half2*)&hu.h[t][2 * j]);
            a = fmaf(hv.x, kq[2 * j], fmaf(hv.y, kq[2 * j + 1], a));
        }
        gate[t] = 1.f / (1.f + __expf(-a * SCALE_));
    }
    if (act) { AGG_CONSUME(1) AGG_ISSUE(2) }
    __syncthreads();

    // ---- P5: hl = (1-g)*hl + g*star (in place); ssq; consume2; issue3 ----
    if (act) {
#pragma unroll
        for (int i = 0; i < 5; ++i) {
            float g = gate[sb + i];
#pragma unroll
            for (int j = 0; j < 4; ++j)
                hl[i][j] = (1.f - g) * hl[i][j] + g * star[d4 + j];
            u.ssq[sb + i][dg] = hl[i][0]*hl[i][0] + hl[i][1]*hl[i][1]
                              + hl[i][2]*hl[i][2] + hl[i][3]*hl[i][3];
        }
        AGG_CONSUME(2) AGG_ISSUE(3)
    }
    __syncthreads();

    // ---- P6: rinv; consume3; issue4 ----
    if (t < S_) {
        float ss = 0.f;
#pragma unroll
        for (int j = 0; j < 25; ++j) ss += u.ssq[t][j];
        rinv[t] = s0 / fmaxf(sqrtf(ss), 1e-12f);
    }
    if (act) { AGG_CONSUME(3) AGG_ISSUE(4) }
    __syncthreads();

    // ---- P7: consume4; normalize hl ----
    if (act) {
        AGG_CONSUME(4)
#pragma unroll
        for (int i = 0; i < 5; ++i) {
            float f = rinv[sb + i];
#pragma unroll
            for (int j = 0; j < 4; ++j) hl[i][j] *= f;
        }
    }
    __syncthreads();   // all agg rows in wu.w; ssq reads (P6) done

    // ---- P8: hg = relu([h | agg] @ Wg); ssq ----
    float o[5][4] = {};
    if (act) {
        const float4* WgQ = (const float4*)Wg;
        for (int k = 0; k < D_; k += 4) {
            float4 w0 = WgQ[(k + 0) * 25 + dg], w1 = WgQ[(k + 1) * 25 + dg],
                   w2 = WgQ[(k + 2) * 25 + dg], w3 = WgQ[(k + 3) * 25 + dg];
            GEMM_STEP_H(o, hu.h, k, w0, w1, w2, w3)
        }
        for (int k = 0; k < D_; k += 4) {
            float4 w0 = WgQ[(D_ + k + 0) * 25 + dg], w1 = WgQ[(D_ + k + 1) * 25 + dg],
                   w2 = WgQ[(D_ + k + 2) * 25 + dg], w3 = WgQ[(D_ + k + 3) * 25 + dg];
            GEMM_STEP(o, wu.w, k, w0, w1, w2, w3)
        }
#pragma unroll
        for (int i = 0; i < 5; ++i) {
#pragma unroll
            for (int j = 0; j < 4; ++j) o[i][j] = fmaxf(o[i][j], 0.f);
            u.ssq[sb + i][dg] = o[i][0]*o[i][0] + o[i][1]*o[i][1]
                              + o[i][2]*o[i][2] + o[i][3]*o[i][3];
        }
    }
    __syncthreads();

    // ---- P9: rinv2 ----
    if (t < S_) {
        float ss = 0.f;
#pragma unroll
        for (int j = 0; j < 25; ++j) ss += u.ssq[t][j];
        rinv2[t] = s1 / fmaxf(sqrtf(ss), 1e-12f);
    }
    __syncthreads();

    // ---- P10: combine + NT store ----
    if (act) {
#pragma unroll
        for (int i = 0; i < 5; ++i) {
            float f = rinv2[sb + i];
            int row = b * S_ + sb + i;
            f4 ov;
            ov.x = hl[i][0] + o[i][0] * f;
            ov.y = hl[i][1] + o[i][1] * f;
            ov.z = hl[i][2] + o[i][2] * f;
            ov.w = hl[i][3] + o[i][3] * f;
            __builtin_nontemporal_store(ov, (f4*)(out + row * D_) + dg);
        }
    }
}

// ---------------------------------------------------------------------------
extern "C" void kernel_launch(void* const* d_in, const int* in_sizes, int n_in,
                              void* d_out, int out_size, void* d_ws, size_t ws_size,
                              hipStream_t stream) {
    (void)in_sizes; (void)n_in; (void)out_size; (void)d_ws; (void)ws_size;
    const int* inputs     = (const int*)d_in[0];
    const float* adj      = (const float*)d_in[1];
    // d_in[2] = item (unused by reference)
    const int* last_items = (const int*)d_in[3];
    const int* adj_items  = (const int*)d_in[4];
    const float* emb      = (const float*)d_in[5];
    const float* sW       = (const float*)d_in[6];
    const float* Wa       = (const float*)d_in[7];
    const float* Wq       = (const float*)d_in[8];
    const float* Wk       = (const float*)d_in[9];
    const float* Wg       = (const float*)d_in[10];
    const float* Wl       = (const float*)d_in[11];
    const int* adj_all    = (const int*)d_in[12];
    const float* num_w    = (const float*)d_in[13];

    float* out = (float*)d_out;

    fused_all<<<2 * B_, 256, 0, stream>>>(inputs, adj, emb, adj_all, num_w,
                                          sW, Wa, Wq, Wk, Wg,
                                          last_items, adj_items, Wl, out);
}